// Round 1
// baseline (380.264 us; speedup 1.0000x reference)
//
#include <hip/hip_runtime.h>
#include <math.h>

#define NCH 64
#define NB 8
#define RSEL 8
#define SPATIAL 110592          // 48*48*48
#define S4 27648                // SPATIAL/4 float4s per channel

// ---------------------------------------------------------------------------
// Kernel 1: per-(b,c) spatial mean. One block per channel-map, 256 threads,
// float4 coalesced streaming, wave shuffle reduce + tiny LDS combine.
// ---------------------------------------------------------------------------
__global__ __launch_bounds__(256) void mean_kernel(const float* __restrict__ x,
                                                   float* __restrict__ means) {
    const int bc = blockIdx.x;  // 0..511  (b*64 + c)
    const float4* p = (const float4*)(x + (size_t)bc * SPATIAL);
    float s = 0.f;
    #pragma unroll 4
    for (int i = threadIdx.x; i < S4; i += 256) {
        float4 v = p[i];
        s += (v.x + v.y) + (v.z + v.w);
    }
    // intra-wave reduction (wave = 64)
    #pragma unroll
    for (int o = 32; o >= 1; o >>= 1) s += __shfl_down(s, o, 64);
    __shared__ float ws[4];
    const int lane = threadIdx.x & 63;
    const int wv   = threadIdx.x >> 6;
    if (lane == 0) ws[wv] = s;
    __syncthreads();
    if (threadIdx.x == 0) {
        float t = (ws[0] + ws[1]) + (ws[2] + ws[3]);
        means[bc] = t * (1.0f / (float)SPATIAL);
    }
}

// ---------------------------------------------------------------------------
// Kernel 2: the whole MLP + sigmoid + top-8, one wave (64 threads).
// Thread j owns output feature j of each linear layer (w rows contiguous).
// Top-k: 8 rounds of butterfly arg-max with lower-index tie-break, matching
// jax.lax.top_k stable-descending semantics.
// ---------------------------------------------------------------------------
__global__ __launch_bounds__(64) void mlp_topk_kernel(const float* __restrict__ means,
                                                      const float* __restrict__ w1,
                                                      const float* __restrict__ b1,
                                                      const float* __restrict__ w2,
                                                      const float* __restrict__ b2,
                                                      int* __restrict__ idx_out) {
    const int j = threadIdx.x;  // 0..63
    __shared__ float m[NB][NCH];
    __shared__ float h[NB][NCH];
    __shared__ float y[NB][NCH];

    #pragma unroll
    for (int b = 0; b < NB; ++b) m[b][j] = means[b * NCH + j];
    __syncthreads();

    // layer 1: h[b][j] = leaky_relu( sum_k m[b][k] * w1[j][k] + b1[j] )
    float wrow[NCH];
    #pragma unroll 8
    for (int k = 0; k < NCH; ++k) wrow[k] = w1[j * NCH + k];
    float bj = b1[j];
    #pragma unroll
    for (int b = 0; b < NB; ++b) {
        float acc = bj;
        #pragma unroll 8
        for (int k = 0; k < NCH; ++k) acc += m[b][k] * wrow[k];
        h[b][j] = acc > 0.f ? acc : 0.01f * acc;
    }
    __syncthreads();

    // layer 2: y[b][j] = sigmoid( sum_k h[b][k] * w2[j][k] + b2[j] )
    #pragma unroll 8
    for (int k = 0; k < NCH; ++k) wrow[k] = w2[j * NCH + k];
    bj = b2[j];
    #pragma unroll
    for (int b = 0; b < NB; ++b) {
        float acc = bj;
        #pragma unroll 8
        for (int k = 0; k < NCH; ++k) acc += h[b][k] * wrow[k];
        y[b][j] = 1.0f / (1.0f + expf(-acc));
    }
    __syncthreads();

    // top-8 per row, descending, ties -> lower index first
    for (int b = 0; b < NB; ++b) {
        float mine = y[b][j];
        #pragma unroll
        for (int r = 0; r < RSEL; ++r) {
            float v = mine;
            int   c = j;
            #pragma unroll
            for (int o = 32; o >= 1; o >>= 1) {
                float ov = __shfl_xor(v, o, 64);
                int   oc = __shfl_xor(c, o, 64);
                if (ov > v || (ov == v && oc < c)) { v = ov; c = oc; }
            }
            if (j == 0) idx_out[b * RSEL + r] = c;
            if (j == c) mine = -INFINITY;  // remove winner for next round
        }
    }
}

// ---------------------------------------------------------------------------
// Kernel 3: gather selected channels. grid = (108, 64): blockIdx.y = (b,r)
// pair, blockIdx.x tiles the 27648 float4s of one channel map.
// ---------------------------------------------------------------------------
__global__ __launch_bounds__(256) void gather_kernel(const float* __restrict__ x,
                                                     const int* __restrict__ idx,
                                                     float* __restrict__ out) {
    const int pair = blockIdx.y;          // 0..63  (b*8 + r)
    const int b    = pair >> 3;
    const int ch   = idx[pair];
    const int off  = blockIdx.x * 256 + threadIdx.x;  // float4 index in map
    const float4* src = (const float4*)(x + (size_t)(b * NCH + ch) * SPATIAL);
    float4*       dst = (float4*)(out + (size_t)pair * SPATIAL);
    dst[off] = src[off];
}

extern "C" void kernel_launch(void* const* d_in, const int* in_sizes, int n_in,
                              void* d_out, int out_size, void* d_ws, size_t ws_size,
                              hipStream_t stream) {
    const float* x  = (const float*)d_in[0];
    const float* w1 = (const float*)d_in[1];
    const float* b1 = (const float*)d_in[2];
    const float* w2 = (const float*)d_in[3];
    const float* b2 = (const float*)d_in[4];
    float* out = (float*)d_out;

    float* means = (float*)d_ws;                              // 512 floats
    int*   idx   = (int*)((char*)d_ws + 512 * sizeof(float)); // 64 ints

    mean_kernel<<<dim3(NB * NCH), dim3(256), 0, stream>>>(x, means);
    mlp_topk_kernel<<<dim3(1), dim3(64), 0, stream>>>(means, w1, b1, w2, b2, idx);
    gather_kernel<<<dim3(S4 / 256, NB * RSEL), dim3(256), 0, stream>>>(x, idx, out);
}

// Round 2
// 376.511 us; speedup vs baseline: 1.0100x; 1.0100x over previous
//
#include <hip/hip_runtime.h>
#include <math.h>

#define NCH 64
#define NB 8
#define RSEL 8
#define SPATIAL 110592          // 48*48*48
#define S4 27648                // SPATIAL/4 float4s per channel
#define PARTS 4                 // split-K partial blocks per channel map
#define CHUNK4 (S4 / PARTS)     // 6912 float4s per partial block
#define ITERS (CHUNK4 / 256)    // 27 float4s per thread

// ---------------------------------------------------------------------------
// Kernel 1: per-(b,c) spatial partial sums. 4 blocks per channel map
// (2048 blocks = 8 blocks/CU = full 32 waves/CU occupancy), 256 threads,
// fully-unrolled float4 streaming so many loads stay in flight.
// ---------------------------------------------------------------------------
__global__ __launch_bounds__(256) void mean_kernel(const float* __restrict__ x,
                                                   float* __restrict__ partials) {
    const int bc   = blockIdx.x >> 2;   // 0..511  (b*64 + c)
    const int part = blockIdx.x & 3;
    const float4* p = (const float4*)(x + (size_t)bc * SPATIAL) + part * CHUNK4;
    float s = 0.f;
    #pragma unroll
    for (int i = 0; i < ITERS; ++i) {
        float4 v = p[i * 256 + threadIdx.x];
        s += (v.x + v.y) + (v.z + v.w);
    }
    // intra-wave reduction (wave = 64)
    #pragma unroll
    for (int o = 32; o >= 1; o >>= 1) s += __shfl_down(s, o, 64);
    __shared__ float ws[4];
    const int lane = threadIdx.x & 63;
    const int wv   = threadIdx.x >> 6;
    if (lane == 0) ws[wv] = s;
    __syncthreads();
    if (threadIdx.x == 0) {
        partials[blockIdx.x] = (ws[0] + ws[1]) + (ws[2] + ws[3]);
    }
}

// ---------------------------------------------------------------------------
// Kernel 2: combine partials -> means, MLP + sigmoid + top-8. One wave.
// Thread j owns output feature j of each linear layer (w rows contiguous).
// ---------------------------------------------------------------------------
__global__ __launch_bounds__(64) void mlp_topk_kernel(const float* __restrict__ partials,
                                                      const float* __restrict__ w1,
                                                      const float* __restrict__ b1,
                                                      const float* __restrict__ w2,
                                                      const float* __restrict__ b2,
                                                      int* __restrict__ idx_out) {
    const int j = threadIdx.x;  // 0..63
    __shared__ float m[NB][NCH];
    __shared__ float h[NB][NCH];
    __shared__ float y[NB][NCH];

    #pragma unroll
    for (int b = 0; b < NB; ++b) {
        const float* pp = partials + (size_t)(b * NCH + j) * PARTS;
        m[b][j] = ((pp[0] + pp[1]) + (pp[2] + pp[3])) * (1.0f / (float)SPATIAL);
    }
    __syncthreads();

    // layer 1: h[b][j] = leaky_relu( sum_k m[b][k] * w1[j][k] + b1[j] )
    float wrow[NCH];
    #pragma unroll 8
    for (int k = 0; k < NCH; ++k) wrow[k] = w1[j * NCH + k];
    float bj = b1[j];
    #pragma unroll
    for (int b = 0; b < NB; ++b) {
        float acc = bj;
        #pragma unroll 8
        for (int k = 0; k < NCH; ++k) acc += m[b][k] * wrow[k];
        h[b][j] = acc > 0.f ? acc : 0.01f * acc;
    }
    __syncthreads();

    // layer 2: y[b][j] = sigmoid( sum_k h[b][k] * w2[j][k] + b2[j] )
    #pragma unroll 8
    for (int k = 0; k < NCH; ++k) wrow[k] = w2[j * NCH + k];
    bj = b2[j];
    #pragma unroll
    for (int b = 0; b < NB; ++b) {
        float acc = bj;
        #pragma unroll 8
        for (int k = 0; k < NCH; ++k) acc += h[b][k] * wrow[k];
        y[b][j] = 1.0f / (1.0f + expf(-acc));
    }
    __syncthreads();

    // top-8 per row, descending, ties -> lower index first
    for (int b = 0; b < NB; ++b) {
        float mine = y[b][j];
        #pragma unroll
        for (int r = 0; r < RSEL; ++r) {
            float v = mine;
            int   c = j;
            #pragma unroll
            for (int o = 32; o >= 1; o >>= 1) {
                float ov = __shfl_xor(v, o, 64);
                int   oc = __shfl_xor(c, o, 64);
                if (ov > v || (ov == v && oc < c)) { v = ov; c = oc; }
            }
            if (j == 0) idx_out[b * RSEL + r] = c;
            if (j == c) mine = -INFINITY;  // remove winner for next round
        }
    }
}

// ---------------------------------------------------------------------------
// Kernel 3: gather selected channels. grid = (27, 64): blockIdx.y = (b,r)
// pair, blockIdx.x tiles the 27648 float4s; 4 float4s per thread for
// latency hiding. Source reads are likely L2/L3 hits (x just streamed).
// ---------------------------------------------------------------------------
__global__ __launch_bounds__(256) void gather_kernel(const float* __restrict__ x,
                                                     const int* __restrict__ idx,
                                                     float* __restrict__ out) {
    const int pair = blockIdx.y;          // 0..63  (b*8 + r)
    const int b    = pair >> 3;
    const int ch   = idx[pair];
    const float4* src = (const float4*)(x + (size_t)(b * NCH + ch) * SPATIAL);
    float4*       dst = (float4*)(out + (size_t)pair * SPATIAL);
    const int base = blockIdx.x * 1024 + threadIdx.x;
    #pragma unroll
    for (int i = 0; i < 4; ++i) {
        dst[base + i * 256] = src[base + i * 256];
    }
}

extern "C" void kernel_launch(void* const* d_in, const int* in_sizes, int n_in,
                              void* d_out, int out_size, void* d_ws, size_t ws_size,
                              hipStream_t stream) {
    const float* x  = (const float*)d_in[0];
    const float* w1 = (const float*)d_in[1];
    const float* b1 = (const float*)d_in[2];
    const float* w2 = (const float*)d_in[3];
    const float* b2 = (const float*)d_in[4];
    float* out = (float*)d_out;

    float* partials = (float*)d_ws;                                     // 2048 floats
    int*   idx      = (int*)((char*)d_ws + NB * NCH * PARTS * sizeof(float)); // 64 ints

    mean_kernel<<<dim3(NB * NCH * PARTS), dim3(256), 0, stream>>>(x, partials);
    mlp_topk_kernel<<<dim3(1), dim3(64), 0, stream>>>(partials, w1, b1, w2, b2, idx);
    gather_kernel<<<dim3(S4 / 1024, NB * RSEL), dim3(256), 0, stream>>>(x, idx, out);
}